// Round 5
// baseline (890.181 us; speedup 1.0000x reference)
//
#include <hip/hip_runtime.h>
#include <stdint.h>

typedef unsigned short u16;
typedef __attribute__((ext_vector_type(8))) short short8;
typedef __attribute__((ext_vector_type(4))) float floatx4;
typedef __attribute__((ext_vector_type(4))) unsigned short u16x4;

#define T_TOK 2048
#define NHEAD 32

__device__ __forceinline__ float bf2f(u16 u) { return __uint_as_float(((unsigned)u) << 16); }
__device__ __forceinline__ u16 f2bf(float f) {
    unsigned u = __float_as_uint(f);
    return (u16)((u + 0x7fffu + ((u >> 16) & 1u)) >> 16);
}

__device__ __forceinline__ floatx4 mfma16(short8 a, short8 b, floatx4 c) {
    return __builtin_amdgcn_mfma_f32_16x16x32_bf16(a, b, c, 0, 0, 0);
}

// ---------------------------------------------------------------------------
// Generic bf16 GEMM, C = A @ B^T.  A: M x K (lda), B: N x K (ldb), C: M x N.
// m97 structure: 128x128 tile, BK=32, global_load_lds width 16, 16x16x32 MFMA.
// ---------------------------------------------------------------------------
__global__ __launch_bounds__(256) void gemm_bt(
    const u16* __restrict__ A, const u16* __restrict__ B, void* __restrict__ Cp,
    int M, int N, int K, int lda, int ldb, int ldc,
    long sA, long sB, long sC, int c_bf16)
{
    __shared__ u16 As[128 * 32];
    __shared__ u16 Bs[128 * 32];
    const int z = blockIdx.z;
    A += (long)z * sA;
    B += (long)z * sB;
    const int tid  = threadIdx.x;
    const int wave = tid >> 6;
    const int lane = tid & 63;
    const long m0 = (long)blockIdx.y * 128;
    const long n0 = (long)blockIdx.x * 128;
    const int wm = (wave & 1) * 64;
    const int wn = (wave >> 1) * 64;
    const int lr = lane & 15;
    const int lk = (lane >> 4) * 8;

    const u16* Ag = A + (m0 + (tid >> 2)) * (long)lda + (tid & 3) * 8;
    const u16* Bg = B + (n0 + (tid >> 2)) * (long)ldb + (tid & 3) * 8;
    const long a64 = (long)64 * lda, b64 = (long)64 * ldb;

    floatx4 acc[4][4] = {};

    for (int k0 = 0; k0 < K; k0 += 32) {
        __syncthreads();
        __builtin_amdgcn_global_load_lds(
            (const __attribute__((address_space(1))) void*)(Ag + k0),
            (__attribute__((address_space(3))) void*)(As + wave * 512), 16, 0, 0);
        __builtin_amdgcn_global_load_lds(
            (const __attribute__((address_space(1))) void*)(Ag + k0 + a64),
            (__attribute__((address_space(3))) void*)(As + 2048 + wave * 512), 16, 0, 0);
        __builtin_amdgcn_global_load_lds(
            (const __attribute__((address_space(1))) void*)(Bg + k0),
            (__attribute__((address_space(3))) void*)(Bs + wave * 512), 16, 0, 0);
        __builtin_amdgcn_global_load_lds(
            (const __attribute__((address_space(1))) void*)(Bg + k0 + b64),
            (__attribute__((address_space(3))) void*)(Bs + 2048 + wave * 512), 16, 0, 0);
        __syncthreads();
        short8 af[4], bfr[4];
#pragma unroll
        for (int t = 0; t < 4; t++) {
            af[t]  = *(const short8*)&As[(wm + t * 16 + lr) * 32 + lk];
            bfr[t] = *(const short8*)&Bs[(wn + t * 16 + lr) * 32 + lk];
        }
#pragma unroll
        for (int mt = 0; mt < 4; mt++)
#pragma unroll
            for (int nt = 0; nt < 4; nt++)
                acc[mt][nt] = mfma16(af[mt], bfr[nt], acc[mt][nt]);
    }

    const int rbase = wm + (lane >> 4) * 4;
    if (c_bf16) {
        u16* C = (u16*)Cp + (long)z * sC;
#pragma unroll
        for (int mt = 0; mt < 4; mt++)
#pragma unroll
            for (int nt = 0; nt < 4; nt++)
#pragma unroll
                for (int r = 0; r < 4; r++) {
                    long row = m0 + rbase + mt * 16 + r;
                    long col = n0 + wn + nt * 16 + lr;
                    C[row * ldc + col] = f2bf(acc[mt][nt][r]);
                }
    } else {
        float* C = (float*)Cp + (long)z * sC;
#pragma unroll
        for (int mt = 0; mt < 4; mt++)
#pragma unroll
            for (int nt = 0; nt < 4; nt++)
#pragma unroll
                for (int r = 0; r < 4; r++) {
                    long row = m0 + rbase + mt * 16 + r;
                    long col = n0 + wn + nt * 16 + lr;
                    C[row * ldc + col] = acc[mt][nt][r];
                }
    }
}

// ---------------------------------------------------------------------------
// Fused causal MLA attention, v7 = v6 + staggered K/V restage (race-free).
// Observation: per chunk, K is read EARLY (QK^T) and V LATE (PV).  So with a
// single buffer each can be restaged as soon as its readers pass a barrier:
//   - K(c+1) issued right after B2 (the Ps barrier: all QK^T Ks-reads done)
//     -> in flight across the whole PV phase (intra-block overlap).
//   - V(c+1) issued after a new raw B3 (post-PV s_barrier).  B3 also CLOSES
//     the latent v6 race (stage(c+1) V-writes vs slow waves' PV Vs-reads).
//   - next half's chunk 0 staged at the last B3, overlapping the epilogue
//     (epilogue barriers are raw lgkm-only so they don't drain vmcnt).
// No mid-loop vmem loads exist (v6 property), so in-flight stages don't
// poison any vmcnt waits (the v4 FIFO failure mode is structurally absent).
// Distinct static LDS arrays keep alias analysis exact (v4 lesson).
// ---------------------------------------------------------------------------
#define ESCALE 0.10411754f   // (1/sqrt(192)) * log2(e)

#define STAGE_K(CIDX)                                                          \
    {                                                                          \
        const u16* ksrc_ = Kp + (long)(CIDX) * 18432 + st_idx;                 \
        _Pragma("unroll")                                                      \
        for (int p_ = 0; p_ < 9; p_++)                                         \
            __builtin_amdgcn_global_load_lds(                                  \
                (const __attribute__((address_space(1))) void*)(ksrc_ + p_ * 2048), \
                (__attribute__((address_space(3))) void*)(Ks + st_idx + p_ * 2048), 16, 0, 0); \
    }
#define STAGE_V(CIDX)                                                          \
    {                                                                          \
        const u16* vsrc_ = Vp + (long)(CIDX) * 16384 + st_idx;                 \
        _Pragma("unroll")                                                      \
        for (int p_ = 0; p_ < 8; p_++)                                         \
            __builtin_amdgcn_global_load_lds(                                  \
                (const __attribute__((address_space(1))) void*)(vsrc_ + p_ * 2048), \
                (__attribute__((address_space(3))) void*)(Vs + st_idx + p_ * 2048), 16, 0, 0); \
    }

__global__ __launch_bounds__(256, 2) void flash_attn(
    const u16* __restrict__ Qp, const u16* __restrict__ Kp,
    const u16* __restrict__ Vp, u16* __restrict__ o_lat)
{
    // Ks[slab s=0..17][fragment-linear 1024 u16], Vs[ct=0..31][512 u16]
    __shared__ __align__(16) u16 Ks[18 * 1024];
    __shared__ __align__(16) u16 Vs[16 * 1024];
    __shared__ __align__(16) u16 Ps[64 * 40];   // P tile 64x32, padded ld 40
    __shared__ float ex[64];

    const int h = blockIdx.y;
    const int tid = threadIdx.x, wave = tid >> 6, lane = tid & 63;
    const int lr = lane & 15, hi = lane >> 4;
    const int wnp = wave * 128;     // O column base for this wave

    // staging index: linear tid*8 across each 2048-u16 block, identical order
    // in global (Kp2/Vp2) and LDS.
    const int st_idx = (wave << 9) + lane * 8;

    // prologue: stage chunk 0 of half 0 (drained by the first __syncthreads)
    STAGE_K(0);
    STAGE_V(0);

    for (int half = 0; half < 2; half++) {
        const int qt = half ? (31 - (int)blockIdx.x) : (int)blockIdx.x;
        const int qb = qt * 64;
        const int nchunks = 2 * qt + 2;

        // persistent Q fragments: wave rows qb + wave*16 + lr, 18 k-slabs
        const u16* Qb = Qp + ((long)h * T_TOK + qb + wave * 16 + lr) * 576 + hi * 8;
        short8 qf[18];
#pragma unroll
        for (int s = 0; s < 18; s++)
            qf[s] = __builtin_nontemporal_load((const short8*)(Qb + s * 32));

        floatx4 oacc[4][8] = {};
        float l_part[4] = {};

        for (int c = 0; c < nchunks; c++) {
            const int jb = c * 32;
            // sync1: drains K(c)/V(c) stages (issued last iteration / prologue)
            __syncthreads();
            // ---- S = Q @ K^T : wave computes 16 q-rows x 32 k-cols ----
            floatx4 sacc[2] = {};
#pragma unroll
            for (int s = 0; s < 18; s++) {
                short8 b0 = *(const short8*)(Ks + s * 1024 + lane * 8);
                short8 b1 = *(const short8*)(Ks + s * 1024 + 512 + lane * 8);
                sacc[0] = mfma16(qf[s], b0, sacc[0]);
                sacc[1] = mfma16(qf[s], b1, sacc[1]);
            }
            // ---- raw-exp2 softmax numerators -> P (LDS), l accumulation ----
            const int qg = qb + wave * 16 + hi * 4;
#pragma unroll
            for (int nt = 0; nt < 2; nt++) {
                const int kg = jb + nt * 16 + lr;
#pragma unroll
                for (int r = 0; r < 4; r++) {
                    float p = (kg <= qg + r) ? exp2f(sacc[nt][r] * ESCALE) : 0.0f;
                    l_part[r] += p;
                    Ps[(wave * 16 + hi * 4 + r) * 40 + nt * 16 + lr] = f2bf(p);
                }
            }
            // B2: Ps visible; ALL waves' Ks reads complete
            __syncthreads();
            // restage K for next chunk now -> overlaps the whole PV phase
            if (c + 1 < nchunks) STAGE_K(c + 1);
            // ---- O += P @ V : all operands in LDS, lane-linear reads ----
            short8 pa[4];
#pragma unroll
            for (int mt = 0; mt < 4; mt++)
                pa[mt] = *(const short8*)(Ps + (mt * 16 + lr) * 40 + hi * 8);
#pragma unroll
            for (int nt = 0; nt < 8; nt++) {
                short8 vb = *(const short8*)(Vs + (wave * 8 + nt) * 512 + lane * 8);
#pragma unroll
                for (int mt = 0; mt < 4; mt++)
                    oacc[mt][nt] = mfma16(pa[mt], vb, oacc[mt][nt]);
            }
            // B3 (raw, no vmcnt drain -> K stays in flight): all Vs reads done
            asm volatile("s_waitcnt lgkmcnt(0)" ::: "memory");
            __builtin_amdgcn_s_barrier();
            __builtin_amdgcn_sched_barrier(0);
            if (c + 1 < nchunks) {
                STAGE_V(c + 1);
            } else if (half == 0) {
                // stage next half's chunk 0; overlaps the epilogue below
                STAGE_K(0);
                STAGE_V(0);
            }
        }

        // ---- finalize row sums (reduce over the 16 lr lanes) ----
#pragma unroll
        for (int r = 0; r < 4; r++) {
            float v = l_part[r];
            v += __shfl_xor(v, 1); v += __shfl_xor(v, 2);
            v += __shfl_xor(v, 4); v += __shfl_xor(v, 8);
            l_part[r] = v;
        }
        if (lr == 0) {
#pragma unroll
            for (int r = 0; r < 4; r++) ex[wave * 16 + hi * 4 + r] = l_part[r];
        }
        // raw barrier (lgkm only) so the next-half stage keeps flying
        asm volatile("s_waitcnt lgkmcnt(0)" ::: "memory");
        __builtin_amdgcn_s_barrier();
        __builtin_amdgcn_sched_barrier(0);
        // ---- O / l -> o_lat[h][t][512] (non-temporal: written once) ----
        const long obase = (long)h * T_TOK + qb;
#pragma unroll
        for (int mt = 0; mt < 4; mt++)
#pragma unroll
            for (int r = 0; r < 4; r++) {
                const int row = mt * 16 + hi * 4 + r;
                const float inv = 1.0f / ex[row];
#pragma unroll
                for (int nt = 0; nt < 8; nt++)
                    __builtin_nontemporal_store(
                        f2bf(oacc[mt][nt][r] * inv),
                        o_lat + (obase + row) * 512 + wnp + nt * 16 + lr);
            }
        // no trailing barrier: the next half's first __syncthreads resyncs;
        // ex[] is not rewritten until after many barriers in the next half.
    }
}

// f32 -> bf16 elementwise cast (n multiple of 4)
__global__ __launch_bounds__(256) void cast_bf16_k(const float* __restrict__ src,
                                                   u16* __restrict__ dst, long n)
{
    long i = ((long)blockIdx.x * 256 + threadIdx.x) * 4;
    if (i + 3 < n) {
        float4 v = *(const float4*)(src + i);
        u16x4 o = { f2bf(v.x), f2bf(v.y), f2bf(v.z), f2bf(v.w) };
        *(u16x4*)(dst + i) = o;
    }
}

// src (R x C) f32 row-major -> dst (Cpad x R) bf16 (transposed)
__global__ void transpose_cast(const float* __restrict__ src, u16* __restrict__ dst,
                               int R, int C, int Cpad)
{
    __shared__ float tile[32][33];
    const int cb = blockIdx.x * 32, rb = blockIdx.y * 32;
    for (int i = threadIdx.y; i < 32; i += 8) {
        int r = rb + i, c = cb + threadIdx.x;
        tile[i][threadIdx.x] = (r < R && c < C) ? src[(long)r * C + c] : 0.0f;
    }
    __syncthreads();
    for (int i = threadIdx.y; i < 32; i += 8) {
        int c = cb + i, r = rb + threadIdx.x;
        if (c < Cpad && r < R) dst[(long)c * R + r] = f2bf(tile[threadIdx.x][i]);
    }
}

// w_uv (KVL=512, H=32, DV=128) f32 -> dst[h][d][r] bf16 (per-head BT layout)
__global__ __launch_bounds__(256) void permute_wuv(const float* __restrict__ src,
                                                   u16* __restrict__ dst)
{
    int idx = blockIdx.x * 256 + threadIdx.x;
    int r = idx & 511;
    int hd = idx >> 9;
    int d = hd & 127, h = hd >> 7;
    dst[idx] = f2bf(src[(long)r * 4096 + h * 128 + d]);
}

// RMSNorm rows (bf16 in/out, fp32 accumulate)
__global__ __launch_bounds__(256) void rmsnorm_rows(const u16* __restrict__ in,
                                                    const float* __restrict__ gamma,
                                                    u16* __restrict__ out, int n, float invn)
{
    const long base = (long)blockIdx.x * n;
    const int tid = threadIdx.x, wave = tid >> 6, lane = tid & 63;
    __shared__ float red[4];
    float ss = 0.f;
    for (int i = tid; i < n; i += 256) { float x = bf2f(in[base + i]); ss += x * x; }
    for (int o = 32; o > 0; o >>= 1) ss += __shfl_xor(ss, o);
    if (lane == 0) red[wave] = ss;
    __syncthreads();
    ss = red[0] + red[1] + red[2] + red[3];
    const float r = rsqrtf(ss * invn + 1e-6f);
    for (int i = tid; i < n; i += 256) {
        float x = bf2f(in[base + i]);
        out[base + i] = f2bf(x * r * gamma[i]);
    }
}

// kv_a post: rmsnorm cols [0,512) -> Kp2 (fragment-order) + Vp2 (fragment-
// order V chunks); rope cols [512,576) -> Kp2 slabs 16,17.  input ld 640.
// Kp2 layout: [chunk j = t>>5][slab-pair p=0..8][2048 u16]: idx within block =
//   wv*512 + ln*8 + (k&7),  wv = (s&1)*2 + (r>>4), ln = (r&15) + 16*((k&31)>>3),
//   r = t&31, s = k>>5.
// Vp2 layout: [chunk j][ct = c>>4][l*8 + e]:  l = (r>>3)*16 + (c&15), e = r&7.
__global__ __launch_bounds__(256) void kv_post(const u16* __restrict__ kva,
                                               const float* __restrict__ gamma,
                                               const int* __restrict__ pos,
                                               u16* __restrict__ Kp2, u16* __restrict__ Vp2)
{
    const int t = blockIdx.x;
    const long base = (long)t * 640;
    const int tid = threadIdx.x, wave = tid >> 6, lane = tid & 63;
    __shared__ float red[4];
    float ss = 0.f;
    for (int i = tid; i < 512; i += 256) { float x = bf2f(kva[base + i]); ss += x * x; }
    for (int o = 32; o > 0; o >>= 1) ss += __shfl_xor(ss, o);
    if (lane == 0) red[wave] = ss;
    __syncthreads();
    ss = red[0] + red[1] + red[2] + red[3];
    const float r = rsqrtf(ss * (1.0f / 512.0f) + 1e-6f);
    const int rr = t & 31, j = t >> 5;
    // Vp2 (fragment-order V chunks)
    {
        const long vbase = (long)j * 16384;
        const int e = rr & 7, lhi = (rr >> 3) * 16;
        for (int i = tid; i < 512; i += 256) {
            float x = bf2f(kva[base + i]) * r * gamma[i];
            const int ct = i >> 4, l = lhi + (i & 15);
            Vp2[vbase + ct * 512 + l * 8 + e] = f2bf(x);
        }
    }
    // Kp2: one aligned 16-B fragment group per thread (72 groups of 8 cols)
    if (tid < 72) {
        const int g  = tid;
        const int i0 = g * 8;
        const int s  = i0 >> 5, p = s >> 1, sb = s & 1, hi2 = (i0 & 31) >> 3;
        const int wv = sb * 2 + (rr >> 4);
        const int ln = (rr & 15) + 16 * hi2;
        const long gidx = (long)j * 18432 + p * 2048 + wv * 512 + ln * 8;
        short8 outv;
        if (g < 64) {
#pragma unroll
            for (int m = 0; m < 8; m++) {
                float x = bf2f(kva[base + i0 + m]) * r * gamma[i0 + m];
                ((u16*)&outv)[m] = f2bf(x);
            }
        } else {
#pragma unroll
            for (int q = 0; q < 4; q++) {
                int jj = ((i0 - 512) >> 1) + q;
                float invf = powf(10000.0f, -(float)jj / 32.0f);
                float ang = (float)pos[t] * invf;
                float sn, cs;
                sincosf(ang, &sn, &cs);
                float x1 = bf2f(kva[base + 512 + 2 * jj]);
                float x2 = bf2f(kva[base + 512 + 2 * jj + 1]);
                ((u16*)&outv)[2 * q]     = f2bf(x1 * cs - x2 * sn);
                ((u16*)&outv)[2 * q + 1] = f2bf(x1 * sn + x2 * cs);
            }
        }
        *(short8*)(Kp2 + gidx) = outv;
    }
}

// rope on q_rope part of q (T,H,192) -> Qp[h][t][512..576]
__global__ __launch_bounds__(256) void rope_q(const u16* __restrict__ q,
                                              const int* __restrict__ pos,
                                              u16* __restrict__ Qp)
{
    int idx = blockIdx.x * 256 + threadIdx.x;    // T*H*32
    int j = idx & 31;
    int h = (idx >> 5) & 31;
    int t = idx >> 10;
    float invf = powf(10000.0f, -(float)j / 32.0f);
    float ang = (float)pos[t] * invf;
    float sn, cs;
    sincosf(ang, &sn, &cs);
    long qb = (long)t * 6144 + h * 192 + 128 + 2 * j;
    float x1 = bf2f(q[qb]), x2 = bf2f(q[qb + 1]);
    long ob = (long)h * T_TOK * 576 + (long)t * 576 + 512 + 2 * j;
    Qp[ob]     = f2bf(x1 * cs - x2 * sn);
    Qp[ob + 1] = f2bf(x1 * sn + x2 * cs);
}

extern "C" void kernel_launch(void* const* d_in, const int* in_sizes, int n_in,
                              void* d_out, int out_size, void* d_ws, size_t ws_size,
                              hipStream_t stream)
{
    const float* hidden = (const float*)d_in[0];
    const int* positions = (const int*)d_in[1];
    const float* w_qa  = (const float*)d_in[2];
    const float* qa_g  = (const float*)d_in[3];
    const float* w_qb  = (const float*)d_in[4];
    const float* w_kva = (const float*)d_in[5];
    const float* kva_g = (const float*)d_in[6];
    const float* w_uk  = (const float*)d_in[7];
    const float* w_uv  = (const float*)d_in[8];
    const float* w_o   = (const float*)d_in[9];

    char* ws = (char*)d_ws;
    // o_lat (64 MB, all 32 heads) aliases the whole early region [0, 67108864):
    // qc/q/hid_bf/wqa_t/qc_raw are all dead before the flash kernel runs.
    u16* o_lat   = (u16*)(ws + 0);
    u16* qc      = (u16*)(ws + 0);
    u16* q       = (u16*)(ws + 6291456);
    u16* hid_bf  = (u16*)(ws + 31457280);
    u16* wqa_t   = (u16*)(ws + 48234496);
    u16* qc_raw  = (u16*)(ws + 60817408);
    u16* wqb_t   = (u16*)(ws + 67108864);
    u16* wkva_t  = (u16*)(ws + 85983232);
    u16* wuk_b   = (u16*)(ws + 91226112);
    u16* wuv_t   = (u16*)(ws + 95420416);
    u16* wo_t    = (u16*)(ws + 99614720);
    u16* kva_raw = (u16*)(ws + 133169152);
    u16* Kp      = (u16*)(ws + 135790592);   // Kp2 fragment-order layout (2.25 MB)
    u16* Vp      = (u16*)(ws + 138149888);   // Vp2 fragment-order layout (2 MB)
    u16* Qp      = (u16*)(ws + 140247040);
    u16* o_v     = Qp;   // alias: Qp dead after attention

    // --- stage 0: casts / relayouts to bf16 ---------------------------------
    cast_bf16_k<<<8192, 256, 0, stream>>>(hidden, hid_bf, 8388608);
    transpose_cast<<<dim3(48, 128),  dim3(32, 8), 0, stream>>>(w_qa,  wqa_t,  4096, 1536, 1536);
    transpose_cast<<<dim3(192, 48),  dim3(32, 8), 0, stream>>>(w_qb,  wqb_t,  1536, 6144, 6144);
    transpose_cast<<<dim3(20, 128),  dim3(32, 8), 0, stream>>>(w_kva, wkva_t, 4096, 576,  640);
    cast_bf16_k<<<2048, 256, 0, stream>>>(w_uk, wuk_b, 2097152);
    permute_wuv<<<8192, 256, 0, stream>>>(w_uv, wuv_t);
    transpose_cast<<<dim3(128, 128), dim3(32, 8), 0, stream>>>(w_o,   wo_t,   4096, 4096, 4096);

    // --- stage 1: LoRA-A projections + norms --------------------------------
    gemm_bt<<<dim3(12, 16, 1), 256, 0, stream>>>(hid_bf, wqa_t, qc_raw,
        2048, 1536, 4096, 4096, 4096, 1536, 0, 0, 0, 1);
    gemm_bt<<<dim3(5, 16, 1), 256, 0, stream>>>(hid_bf, wkva_t, kva_raw,
        2048, 640, 4096, 4096, 4096, 640, 0, 0, 0, 1);
    rmsnorm_rows<<<2048, 256, 0, stream>>>(qc_raw, qa_g, qc, 1536, 1.0f / 1536.0f);
    kv_post<<<2048, 256, 0, stream>>>(kva_raw, kva_g, positions, Kp, Vp);

    // --- stage 2: q up-projection, rope, per-head absorb --------------------
    gemm_bt<<<dim3(48, 16, 1), 256, 0, stream>>>(qc, wqb_t, q,
        2048, 6144, 1536, 1536, 1536, 6144, 0, 0, 0, 1);
    rope_q<<<8192, 256, 0, stream>>>(q, positions, Qp);
    gemm_bt<<<dim3(4, 16, 32), 256, 0, stream>>>(q, wuk_b, Qp,
        2048, 512, 128, 6144, 4096, 576, 192, 128, (long)2048 * 576, 1);

    // --- stage 3: fused causal attention (one dispatch, balanced pairs) -----
    flash_attn<<<dim3(16, 32), 256, 0, stream>>>(Qp, Kp, Vp, o_lat);

    // --- stage 4: o_v and output projection ---------------------------------
    gemm_bt<<<dim3(1, 16, 32), 256, 0, stream>>>(o_lat, wuv_t, o_v,
        2048, 128, 512, 512, 512, 4096, (long)2048 * 512, 65536, 128, 1);
    gemm_bt<<<dim3(32, 16, 1), 256, 0, stream>>>(o_v, wo_t, d_out,
        2048, 4096, 4096, 4096, 4096, 4096, 0, 0, 0, 0);
}

// Round 6
// 725.868 us; speedup vs baseline: 1.2264x; 1.2264x over previous
//
#include <hip/hip_runtime.h>
#include <stdint.h>

typedef unsigned short u16;
typedef __attribute__((ext_vector_type(8))) short short8;
typedef __attribute__((ext_vector_type(4))) float floatx4;
typedef __attribute__((ext_vector_type(4))) unsigned short u16x4;

#define T_TOK 2048
#define NHEAD 32

__device__ __forceinline__ float bf2f(u16 u) { return __uint_as_float(((unsigned)u) << 16); }
__device__ __forceinline__ u16 f2bf(float f) {
    unsigned u = __float_as_uint(f);
    return (u16)((u + 0x7fffu + ((u >> 16) & 1u)) >> 16);
}

__device__ __forceinline__ floatx4 mfma16(short8 a, short8 b, floatx4 c) {
    return __builtin_amdgcn_mfma_f32_16x16x32_bf16(a, b, c, 0, 0, 0);
}

// ---------------------------------------------------------------------------
// Generic bf16 GEMM, C = A @ B^T.  A: M x K (lda), B: N x K (ldb), C: M x N.
// m97 structure: 128x128 tile, BK=32, global_load_lds width 16, 16x16x32 MFMA.
// z-dim batches via sA/sB/sC -- also usable as a K-split (sA=sB=K_half,
// sC = whole-C stride -> partial sums in separate buffers).
// ---------------------------------------------------------------------------
__global__ __launch_bounds__(256) void gemm_bt(
    const u16* __restrict__ A, const u16* __restrict__ B, void* __restrict__ Cp,
    int M, int N, int K, int lda, int ldb, int ldc,
    long sA, long sB, long sC, int c_bf16)
{
    __shared__ u16 As[128 * 32];
    __shared__ u16 Bs[128 * 32];
    const int z = blockIdx.z;
    A += (long)z * sA;
    B += (long)z * sB;
    const int tid  = threadIdx.x;
    const int wave = tid >> 6;
    const int lane = tid & 63;
    const long m0 = (long)blockIdx.y * 128;
    const long n0 = (long)blockIdx.x * 128;
    const int wm = (wave & 1) * 64;
    const int wn = (wave >> 1) * 64;
    const int lr = lane & 15;
    const int lk = (lane >> 4) * 8;

    const u16* Ag = A + (m0 + (tid >> 2)) * (long)lda + (tid & 3) * 8;
    const u16* Bg = B + (n0 + (tid >> 2)) * (long)ldb + (tid & 3) * 8;
    const long a64 = (long)64 * lda, b64 = (long)64 * ldb;

    floatx4 acc[4][4] = {};

    for (int k0 = 0; k0 < K; k0 += 32) {
        __syncthreads();
        __builtin_amdgcn_global_load_lds(
            (const __attribute__((address_space(1))) void*)(Ag + k0),
            (__attribute__((address_space(3))) void*)(As + wave * 512), 16, 0, 0);
        __builtin_amdgcn_global_load_lds(
            (const __attribute__((address_space(1))) void*)(Ag + k0 + a64),
            (__attribute__((address_space(3))) void*)(As + 2048 + wave * 512), 16, 0, 0);
        __builtin_amdgcn_global_load_lds(
            (const __attribute__((address_space(1))) void*)(Bg + k0),
            (__attribute__((address_space(3))) void*)(Bs + wave * 512), 16, 0, 0);
        __builtin_amdgcn_global_load_lds(
            (const __attribute__((address_space(1))) void*)(Bg + k0 + b64),
            (__attribute__((address_space(3))) void*)(Bs + 2048 + wave * 512), 16, 0, 0);
        __syncthreads();
        short8 af[4], bfr[4];
#pragma unroll
        for (int t = 0; t < 4; t++) {
            af[t]  = *(const short8*)&As[(wm + t * 16 + lr) * 32 + lk];
            bfr[t] = *(const short8*)&Bs[(wn + t * 16 + lr) * 32 + lk];
        }
#pragma unroll
        for (int mt = 0; mt < 4; mt++)
#pragma unroll
            for (int nt = 0; nt < 4; nt++)
                acc[mt][nt] = mfma16(af[mt], bfr[nt], acc[mt][nt]);
    }

    const int rbase = wm + (lane >> 4) * 4;
    if (c_bf16) {
        u16* C = (u16*)Cp + (long)z * sC;
#pragma unroll
        for (int mt = 0; mt < 4; mt++)
#pragma unroll
            for (int nt = 0; nt < 4; nt++)
#pragma unroll
                for (int r = 0; r < 4; r++) {
                    long row = m0 + rbase + mt * 16 + r;
                    long col = n0 + wn + nt * 16 + lr;
                    C[row * ldc + col] = f2bf(acc[mt][nt][r]);
                }
    } else {
        float* C = (float*)Cp + (long)z * sC;
#pragma unroll
        for (int mt = 0; mt < 4; mt++)
#pragma unroll
            for (int nt = 0; nt < 4; nt++)
#pragma unroll
                for (int r = 0; r < 4; r++) {
                    long row = m0 + rbase + mt * 16 + r;
                    long col = n0 + wn + nt * 16 + lr;
                    C[row * ldc + col] = acc[mt][nt][r];
                }
    }
}

// ---------------------------------------------------------------------------
// Fused causal MLA attention, v7 (UNCHANGED from round 5 -- at its structural
// plateau: ~214us, ~700 TF effective, MfmaUtil ~31%).
// ---------------------------------------------------------------------------
#define ESCALE 0.10411754f   // (1/sqrt(192)) * log2(e)

#define STAGE_K(CIDX)                                                          \
    {                                                                          \
        const u16* ksrc_ = Kp + (long)(CIDX) * 18432 + st_idx;                 \
        _Pragma("unroll")                                                      \
        for (int p_ = 0; p_ < 9; p_++)                                         \
            __builtin_amdgcn_global_load_lds(                                  \
                (const __attribute__((address_space(1))) void*)(ksrc_ + p_ * 2048), \
                (__attribute__((address_space(3))) void*)(Ks + st_idx + p_ * 2048), 16, 0, 0); \
    }
#define STAGE_V(CIDX)                                                          \
    {                                                                          \
        const u16* vsrc_ = Vp + (long)(CIDX) * 16384 + st_idx;                 \
        _Pragma("unroll")                                                      \
        for (int p_ = 0; p_ < 8; p_++)                                         \
            __builtin_amdgcn_global_load_lds(                                  \
                (const __attribute__((address_space(1))) void*)(vsrc_ + p_ * 2048), \
                (__attribute__((address_space(3))) void*)(Vs + st_idx + p_ * 2048), 16, 0, 0); \
    }

__global__ __launch_bounds__(256, 2) void flash_attn(
    const u16* __restrict__ Qp, const u16* __restrict__ Kp,
    const u16* __restrict__ Vp, u16* __restrict__ o_lat)
{
    __shared__ __align__(16) u16 Ks[18 * 1024];
    __shared__ __align__(16) u16 Vs[16 * 1024];
    __shared__ __align__(16) u16 Ps[64 * 40];   // P tile 64x32, padded ld 40
    __shared__ float ex[64];

    const int h = blockIdx.y;
    const int tid = threadIdx.x, wave = tid >> 6, lane = tid & 63;
    const int lr = lane & 15, hi = lane >> 4;
    const int wnp = wave * 128;

    const int st_idx = (wave << 9) + lane * 8;

    STAGE_K(0);
    STAGE_V(0);

    for (int half = 0; half < 2; half++) {
        const int qt = half ? (31 - (int)blockIdx.x) : (int)blockIdx.x;
        const int qb = qt * 64;
        const int nchunks = 2 * qt + 2;

        const u16* Qb = Qp + ((long)h * T_TOK + qb + wave * 16 + lr) * 576 + hi * 8;
        short8 qf[18];
#pragma unroll
        for (int s = 0; s < 18; s++)
            qf[s] = __builtin_nontemporal_load((const short8*)(Qb + s * 32));

        floatx4 oacc[4][8] = {};
        float l_part[4] = {};

        for (int c = 0; c < nchunks; c++) {
            const int jb = c * 32;
            __syncthreads();
            floatx4 sacc[2] = {};
#pragma unroll
            for (int s = 0; s < 18; s++) {
                short8 b0 = *(const short8*)(Ks + s * 1024 + lane * 8);
                short8 b1 = *(const short8*)(Ks + s * 1024 + 512 + lane * 8);
                sacc[0] = mfma16(qf[s], b0, sacc[0]);
                sacc[1] = mfma16(qf[s], b1, sacc[1]);
            }
            const int qg = qb + wave * 16 + hi * 4;
#pragma unroll
            for (int nt = 0; nt < 2; nt++) {
                const int kg = jb + nt * 16 + lr;
#pragma unroll
                for (int r = 0; r < 4; r++) {
                    float p = (kg <= qg + r) ? exp2f(sacc[nt][r] * ESCALE) : 0.0f;
                    l_part[r] += p;
                    Ps[(wave * 16 + hi * 4 + r) * 40 + nt * 16 + lr] = f2bf(p);
                }
            }
            __syncthreads();
            if (c + 1 < nchunks) STAGE_K(c + 1);
            short8 pa[4];
#pragma unroll
            for (int mt = 0; mt < 4; mt++)
                pa[mt] = *(const short8*)(Ps + (mt * 16 + lr) * 40 + hi * 8);
#pragma unroll
            for (int nt = 0; nt < 8; nt++) {
                short8 vb = *(const short8*)(Vs + (wave * 8 + nt) * 512 + lane * 8);
#pragma unroll
                for (int mt = 0; mt < 4; mt++)
                    oacc[mt][nt] = mfma16(pa[mt], vb, oacc[mt][nt]);
            }
            asm volatile("s_waitcnt lgkmcnt(0)" ::: "memory");
            __builtin_amdgcn_s_barrier();
            __builtin_amdgcn_sched_barrier(0);
            if (c + 1 < nchunks) {
                STAGE_V(c + 1);
            } else if (half == 0) {
                STAGE_K(0);
                STAGE_V(0);
            }
        }

#pragma unroll
        for (int r = 0; r < 4; r++) {
            float v = l_part[r];
            v += __shfl_xor(v, 1); v += __shfl_xor(v, 2);
            v += __shfl_xor(v, 4); v += __shfl_xor(v, 8);
            l_part[r] = v;
        }
        if (lr == 0) {
#pragma unroll
            for (int r = 0; r < 4; r++) ex[wave * 16 + hi * 4 + r] = l_part[r];
        }
        asm volatile("s_waitcnt lgkmcnt(0)" ::: "memory");
        __builtin_amdgcn_s_barrier();
        __builtin_amdgcn_sched_barrier(0);
        const long obase = (long)h * T_TOK + qb;
#pragma unroll
        for (int mt = 0; mt < 4; mt++)
#pragma unroll
            for (int r = 0; r < 4; r++) {
                const int row = mt * 16 + hi * 4 + r;
                const float inv = 1.0f / ex[row];
#pragma unroll
                for (int nt = 0; nt < 8; nt++)
                    __builtin_nontemporal_store(
                        f2bf(oacc[mt][nt][r] * inv),
                        o_lat + (obase + row) * 512 + wnp + nt * 16 + lr);
            }
    }
}

// ---------------------------------------------------------------------------
// mega_prep: ALL stage-0 relayouts in one dispatch (range-dispatched 1D grid).
//   [0,8192)       cast hidden f32->bf16 (8,388,608 elems)
//   [8192,10240)   cast w_uk   f32->bf16 (2,097,152 elems)
//   [10240,18432)  permute w_uv -> wuv_t[h][d][r]
//   [18432,24576)  transpose w_qa  (4096x1536) -> comb rows 0..1535
//   [24576,27136)  transpose w_kva (4096x576)  -> comb rows 1536..2175 (zero-pad)
//   [27136,36352)  transpose w_qb  (1536x6144) -> wqb_t
//   [36352,52736)  transpose w_o   (4096x4096) -> wo_t
// ---------------------------------------------------------------------------
__global__ __launch_bounds__(256) void mega_prep(
    const float* __restrict__ hidden, const float* __restrict__ w_qa,
    const float* __restrict__ w_kva, const float* __restrict__ w_qb,
    const float* __restrict__ w_o, const float* __restrict__ w_uk,
    const float* __restrict__ w_uv,
    u16* __restrict__ hid_bf, u16* __restrict__ comb, u16* __restrict__ wqb_t,
    u16* __restrict__ wo_t, u16* __restrict__ wuk_b, u16* __restrict__ wuv_t)
{
    __shared__ float tile[32][33];
    const int bid = blockIdx.x, tid = threadIdx.x;

    if (bid < 8192) {                       // cast hidden
        long i = ((long)bid * 256 + tid) * 4;
        float4 v = *(const float4*)(hidden + i);
        u16x4 o = { f2bf(v.x), f2bf(v.y), f2bf(v.z), f2bf(v.w) };
        *(u16x4*)(hid_bf + i) = o;
        return;
    }
    if (bid < 10240) {                      // cast w_uk
        long i = ((long)(bid - 8192) * 256 + tid) * 4;
        float4 v = *(const float4*)(w_uk + i);
        u16x4 o = { f2bf(v.x), f2bf(v.y), f2bf(v.z), f2bf(v.w) };
        *(u16x4*)(wuk_b + i) = o;
        return;
    }
    if (bid < 18432) {                      // permute w_uv
        int idx = (bid - 10240) * 256 + tid;
        int r = idx & 511;
        int hd = idx >> 9;
        int d = hd & 127, h = hd >> 7;
        wuv_t[idx] = f2bf(w_uv[(long)r * 4096 + h * 128 + d]);
        return;
    }
    // transpose branches
    const float* src; u16* dst; int R, C, Cpad, l, gw;
    if (bid < 24576)      { l = bid - 18432; gw = 48;  src = w_qa;  dst = comb;                 R = 4096; C = 1536; Cpad = 1536; }
    else if (bid < 27136) { l = bid - 24576; gw = 20;  src = w_kva; dst = comb + 1536 * 4096;   R = 4096; C = 576;  Cpad = 640;  }
    else if (bid < 36352) { l = bid - 27136; gw = 192; src = w_qb;  dst = wqb_t;                R = 1536; C = 6144; Cpad = 6144; }
    else                  { l = bid - 36352; gw = 128; src = w_o;   dst = wo_t;                 R = 4096; C = 4096; Cpad = 4096; }
    const int cb = (l % gw) * 32, rb = (l / gw) * 32;
    const int tx = tid & 31, ty = tid >> 5;
    for (int i = ty; i < 32; i += 8) {
        int r = rb + i, c = cb + tx;
        tile[i][tx] = (r < R && c < C) ? src[(long)r * C + c] : 0.0f;
    }
    __syncthreads();
    for (int i = ty; i < 32; i += 8) {
        int c = cb + i, r = rb + tx;
        if (c < Cpad && r < R) dst[(long)c * R + r] = f2bf(tile[tx][i]);
    }
}

// ---------------------------------------------------------------------------
// post_stage1: consumes the two f32 K-split partials of the merged qa+kva
// GEMM (row = p0+p1), applies BOTH rmsnorms, writes qc (bf16), Kp2/Vp2
// (fragment-order) and the k-rope slabs.  One pass, one dispatch.
// Kp2 layout: [chunk j=t>>5][slab-pair p=0..8][2048 u16]: idx = wv*512+ln*8+(k&7),
//   wv=(s&1)*2+(rr>>4), ln=(rr&15)+16*((k&31)>>3), rr=t&31, s=k>>5.
// Vp2 layout: [chunk j][ct=c>>4][l*8+e]: l=(rr>>3)*16+(c&15), e=rr&7.
// ---------------------------------------------------------------------------
__global__ __launch_bounds__(256) void post_stage1(
    const float* __restrict__ p0, const float* __restrict__ p1,
    const float* __restrict__ qa_g, const float* __restrict__ kva_g,
    const int* __restrict__ pos,
    u16* __restrict__ qc, u16* __restrict__ Kp2, u16* __restrict__ Vp2)
{
    const int t = blockIdx.x;
    const int tid = threadIdx.x, wave = tid >> 6, lane = tid & 63;
    __shared__ float row[2176];
    __shared__ float red1[4], red2[4];
    const long b = (long)t * 2176;
    float s1 = 0.f, s2 = 0.f;
    for (int i = tid; i < 2176; i += 256) {
        float v = p0[b + i] + p1[b + i];
        row[i] = v;
        if (i < 1536) s1 += v * v;
        else if (i < 2048) s2 += v * v;
    }
    for (int o = 32; o > 0; o >>= 1) { s1 += __shfl_xor(s1, o); s2 += __shfl_xor(s2, o); }
    if (lane == 0) { red1[wave] = s1; red2[wave] = s2; }
    __syncthreads();
    s1 = red1[0] + red1[1] + red1[2] + red1[3];
    s2 = red2[0] + red2[1] + red2[2] + red2[3];
    const float r1 = rsqrtf(s1 * (1.0f / 1536.0f) + 1e-6f);
    const float r2 = rsqrtf(s2 * (1.0f / 512.0f) + 1e-6f);
    // q_c rmsnorm -> qc
    for (int i = tid; i < 1536; i += 256)
        qc[(long)t * 1536 + i] = f2bf(row[i] * r1 * qa_g[i]);
    const int rr = t & 31, j = t >> 5;
    // Vp2
    {
        const long vbase = (long)j * 16384;
        const int e = rr & 7, lhi = (rr >> 3) * 16;
        for (int i = tid; i < 512; i += 256) {
            float x = row[1536 + i] * r2 * kva_g[i];
            const int ct = i >> 4, l = lhi + (i & 15);
            Vp2[vbase + ct * 512 + l * 8 + e] = f2bf(x);
        }
    }
    // Kp2: one aligned 16-B fragment group per thread (72 groups of 8 cols)
    if (tid < 72) {
        const int g  = tid;
        const int i0 = g * 8;
        const int s  = i0 >> 5, p = s >> 1, sb = s & 1, hi2 = (i0 & 31) >> 3;
        const int wv = sb * 2 + (rr >> 4);
        const int ln = (rr & 15) + 16 * hi2;
        const long gidx = (long)j * 18432 + p * 2048 + wv * 512 + ln * 8;
        short8 outv;
        if (g < 64) {
#pragma unroll
            for (int m = 0; m < 8; m++)
                ((u16*)&outv)[m] = f2bf(row[1536 + i0 + m] * r2 * kva_g[i0 + m]);
        } else {
#pragma unroll
            for (int q_ = 0; q_ < 4; q_++) {
                int jj = ((i0 - 512) >> 1) + q_;
                float invf = exp2f(-(float)jj * 0.4152410119f);  // 10000^(-jj/32)
                float ang = (float)pos[t] * invf;
                float sn, cs;
                sincosf(ang, &sn, &cs);
                float x1 = row[2048 + 2 * jj];
                float x2 = row[2048 + 2 * jj + 1];
                ((u16*)&outv)[2 * q_]     = f2bf(x1 * cs - x2 * sn);
                ((u16*)&outv)[2 * q_ + 1] = f2bf(x1 * sn + x2 * cs);
            }
        }
        *(short8*)(Kp2 + gidx) = outv;
    }
}

// rope on q_rope part of q (T,H,192) -> Qp[h][t][512..576]
__global__ __launch_bounds__(256) void rope_q(const u16* __restrict__ q,
                                              const int* __restrict__ pos,
                                              u16* __restrict__ Qp)
{
    int idx = blockIdx.x * 256 + threadIdx.x;    // T*H*32
    int j = idx & 31;
    int h = (idx >> 5) & 31;
    int t = idx >> 10;
    float invf = exp2f(-(float)j * 0.4152410119f);  // 10000^(-j/32)
    float ang = (float)pos[t] * invf;
    float sn, cs;
    sincosf(ang, &sn, &cs);
    long qb = (long)t * 6144 + h * 192 + 128 + 2 * j;
    float x1 = bf2f(q[qb]), x2 = bf2f(q[qb + 1]);
    long ob = (long)h * T_TOK * 576 + (long)t * 576 + 512 + 2 * j;
    Qp[ob]     = f2bf(x1 * cs - x2 * sn);
    Qp[ob + 1] = f2bf(x1 * sn + x2 * cs);
}

extern "C" void kernel_launch(void* const* d_in, const int* in_sizes, int n_in,
                              void* d_out, int out_size, void* d_ws, size_t ws_size,
                              hipStream_t stream)
{
    const float* hidden = (const float*)d_in[0];
    const int* positions = (const int*)d_in[1];
    const float* w_qa  = (const float*)d_in[2];
    const float* qa_g  = (const float*)d_in[3];
    const float* w_qb  = (const float*)d_in[4];
    const float* w_kva = (const float*)d_in[5];
    const float* kva_g = (const float*)d_in[6];
    const float* w_uk  = (const float*)d_in[7];
    const float* w_uv  = (const float*)d_in[8];
    const float* w_o   = (const float*)d_in[9];

    char* ws = (char*)d_ws;
    // Memory map (aliasing by lifetime; all early buffers dead before flash):
    //   [0,16.8M)        hid_bf   (stage0 -> stage1);  qc aliases [0,6.3M) after
    //   [16.8M,34.6M)    comb     (stage0 -> stage1);  q aliases [16.8M,42.0M) after
    //   [34.6M,52.4M)    p0 f32 partial (stage1 -> post_stage1)
    //   [52.4M,70.3M)    p1 f32 partial (stage1 -> post_stage1)
    //   [0,67.1M)        o_lat aliases everything above (flash -> uv GEMM)
    //   [70.3M+)         persistent weights, Kp/Vp/Qp
    u16*   hid_bf = (u16*)(ws + 0);
    u16*   qc     = (u16*)(ws + 0);           // alias: hid_bf dead when written
    u16*   comb   = (u16*)(ws + 16777216);
    u16*   q      = (u16*)(ws + 16777216);    // alias: comb/p0 dead when written
    float* p0     = (float*)(ws + 34603008);
    float* p1     = (float*)(ws + 52428800);  // = p0 + 2048*2176 floats
    u16*   o_lat  = (u16*)(ws + 0);           // alias: all early dead before flash
    u16*   wqb_t  = (u16*)(ws + 70254592);
    u16*   wuk_b  = (u16*)(ws + 89128960);
    u16*   wuv_t  = (u16*)(ws + 93323264);
    u16*   wo_t   = (u16*)(ws + 97517568);
    u16*   Kp     = (u16*)(ws + 131072000);
    u16*   Vp     = (u16*)(ws + 133431296);
    u16*   Qp     = (u16*)(ws + 135528448);   // ends at 211,025,920
    u16*   o_v    = Qp;                       // alias: Qp dead after attention

    // --- stage 0: all relayouts in ONE dispatch -----------------------------
    mega_prep<<<52736, 256, 0, stream>>>(hidden, w_qa, w_kva, w_qb, w_o, w_uk, w_uv,
                                         hid_bf, comb, wqb_t, wo_t, wuk_b, wuv_t);

    // --- stage 1: merged qa+kva projection, K-split x2 (f32 partials) -------
    // C = hid_bf @ comb^T, N=2176 (1536 qa | 640 kva), K split 2x2048:
    // grid (17,16,2) = 544 blocks -> full chip at 2-deep occupancy.
    gemm_bt<<<dim3(17, 16, 2), 256, 0, stream>>>(hid_bf, comb, p0,
        2048, 2176, 2048, 4096, 4096, 2176, 2048, 2048, (long)2048 * 2176, 0);
    post_stage1<<<2048, 256, 0, stream>>>(p0, p1, qa_g, kva_g, positions, qc, Kp, Vp);

    // --- stage 2: q up-projection, rope, per-head absorb --------------------
    gemm_bt<<<dim3(48, 16, 1), 256, 0, stream>>>(qc, wqb_t, q,
        2048, 6144, 1536, 1536, 1536, 6144, 0, 0, 0, 1);
    rope_q<<<8192, 256, 0, stream>>>(q, positions, Qp);
    gemm_bt<<<dim3(4, 16, 32), 256, 0, stream>>>(q, wuk_b, Qp,
        2048, 512, 128, 6144, 4096, 576, 192, 128, (long)2048 * 576, 1);

    // --- stage 3: fused causal attention (one dispatch, balanced pairs) -----
    flash_attn<<<dim3(16, 32), 256, 0, stream>>>(Qp, Kp, Vp, o_lat);

    // --- stage 4: o_v and output projection ---------------------------------
    gemm_bt<<<dim3(1, 16, 32), 256, 0, stream>>>(o_lat, wuv_t, o_v,
        2048, 128, 512, 512, 512, 4096, (long)2048 * 512, 65536, 128, 1);
    gemm_bt<<<dim3(32, 16, 1), 256, 0, stream>>>(o_v, wo_t, d_out,
        2048, 4096, 4096, 4096, 4096, 4096, 0, 0, 0, 0);
}